// Round 12
// baseline (942.842 us; speedup 1.0000x reference)
//
#include <hip/hip_runtime.h>

typedef _Float16 f16;
typedef f16 f16x8 __attribute__((ext_vector_type(8)));
typedef f16 f16x4 __attribute__((ext_vector_type(4)));
typedef float f32x4 __attribute__((ext_vector_type(4)));

#define HID 5120
#define QKVO 7208
#define S_TOK 2048
#define NQH 40
#define NKV 8
#define HD 128

__device__ __forceinline__ void gload16(const void* g, void* l) {
    __builtin_amdgcn_global_load_lds(
        (const __attribute__((address_space(1))) void*)g,
        (__attribute__((address_space(3))) void*)l,
        16, 0, 0);
}

// ---------------- stage 1: stable partition of tokens by modality ----------------
__global__ void sort_tokens(const int* __restrict__ mod, int* __restrict__ sorted,
                            int* __restrict__ offs)
{
    int tid = threadIdx.x, wave = tid >> 6, lane = tid & 63;
    int mloc[8];
    int c[3] = {0, 0, 0};
#pragma unroll
    for (int j = 0; j < 8; ++j) {
        int m = mod[tid * 8 + j];
        mloc[j] = m;
        c[m]++;
    }
    __shared__ int wsum[4][3];
    int excl[3];
#pragma unroll
    for (int m = 0; m < 3; ++m) {
        int v = c[m];
        int incl = v;
        for (int d = 1; d < 64; d <<= 1) {
            int n = __shfl_up(incl, d, 64);
            if (lane >= d) incl += n;
        }
        excl[m] = incl - v;
        if (lane == 63) wsum[wave][m] = incl;
    }
    __syncthreads();
    int wbase[3], tot[3];
#pragma unroll
    for (int m = 0; m < 3; ++m) {
        int b = 0, t = 0;
        for (int w = 0; w < 4; ++w) {
            if (w < wave) b += wsum[w][m];
            t += wsum[w][m];
        }
        wbase[m] = b;
        tot[m] = t;
    }
    int base[3];
    base[0] = 0;
    base[1] = tot[0];
    base[2] = tot[0] + tot[1];
    if (tid == 0) {
        offs[0] = 0;
        offs[1] = tot[0];
        offs[2] = tot[0] + tot[1];
        offs[3] = S_TOK;
    }
    int pos[3];
#pragma unroll
    for (int m = 0; m < 3; ++m) pos[m] = base[m] + wbase[m] + excl[m];
#pragma unroll
    for (int j = 0; j < 8; ++j) {
        int m = mloc[j];
        sorted[pos[m]++] = tid * 8 + j;
    }
}

// ---------------- stage 2: fp32 -> fp16 weight conversion ----------------
__global__ void cvt_f32_f16(const float* __restrict__ src, f16* __restrict__ dst, int n4)
{
    int i = blockIdx.x * 256 + threadIdx.x;
    int stride = gridDim.x * 256;
    const float4* s4 = (const float4*)src;
    f16x4* d4 = (f16x4*)dst;
    for (; i < n4; i += stride) {
        float4 a = s4[i];
        f16x4 h;
        h[0] = (f16)a.x; h[1] = (f16)a.y; h[2] = (f16)a.z; h[3] = (f16)a.w;
        d4[i] = h;
    }
}

// ---------------- stage 3: pre RMS norm -> fp16 activations (token order) ----------------
__global__ void rms_pre(const float* __restrict__ x, const int* __restrict__ mod,
                        const float* __restrict__ prenorm, f16* __restrict__ A1)
{
    int tok = blockIdx.x, tid = threadIdx.x;
    int m = mod[tok];
    const float4* xv = (const float4*)(x + (size_t)tok * HID);
    float4 v[5];
    float ss = 0.f;
#pragma unroll
    for (int j = 0; j < 5; ++j) {
        v[j] = xv[tid + 256 * j];
        ss += v[j].x * v[j].x + v[j].y * v[j].y + v[j].z * v[j].z + v[j].w * v[j].w;
    }
    for (int d = 1; d < 64; d <<= 1) ss += __shfl_xor(ss, d, 64);
    __shared__ float ws[4];
    if ((tid & 63) == 0) ws[tid >> 6] = ss;
    __syncthreads();
    float tot = ws[0] + ws[1] + ws[2] + ws[3];
    float inv = rsqrtf(tot * (1.f / HID) + 1e-6f);
    const float4* wv = (const float4*)(prenorm + (size_t)m * HID);
    f16x4* out4 = (f16x4*)(A1 + (size_t)tok * HID);
#pragma unroll
    for (int j = 0; j < 5; ++j) {
        float4 w = wv[tid + 256 * j];
        f16x4 h;
        h[0] = (f16)(v[j].x * inv * w.x);
        h[1] = (f16)(v[j].y * inv * w.y);
        h[2] = (f16)(v[j].z * inv * w.z);
        h[3] = (f16)(v[j].w * inv * w.w);
        out4[tid + 256 * j] = h;
    }
}

// ---------------- grouped GEMM, 256x256 tile, 8-phase schedule (T2+T3+T4+T5) ----------------
// A fp16 [2048][5120] gathered rows; W fp16 [3][NW][5120]; C fp32 scattered.
// 8 waves (2M x 4N), wave tile 128x64, acc[8][4]. LDS 128KB: As/Bs x 2 buffers
// (buf0 = even K-tiles, buf1 = odd). Per iter (2 K-tiles, 8 phases):
//   ph0-3: compute quadrants 0-3 of even tile (buf0); stage odd tile's 4 half-tiles -> buf1
//   ph4-7: compute odd tile (buf1); stage next even tile -> buf0
// Gate at ph0/ph4: issue own 2-load stage, vmcnt(2) (drains exactly the consumed
// tile's 8 loads), barrier (other waves' loads), then ds_reads. B-frags loaded once
// per K-tile and held 4 phases. XCD-panel-grouped grid: F=((P>>3)*8+mt)*8+(P&7).
__global__ __launch_bounds__(512, 2) void gemm_grouped8(
    const f16* __restrict__ A, const f16* __restrict__ W,
    float* __restrict__ C,
    const int* __restrict__ sorted_tok,
    const int* __restrict__ mod_off, int NW, int NTN, int NPAN)
{
    const int K = HID;
    const int NIT = K / 128;  // 40 iterations, 2 K-tiles each
    int F = blockIdx.x;
    int g = F & 7, s = F >> 3;
    int P = (s >> 3) * 8 + g;
    if (P >= NPAN) return;
    int mt = s & 7;
    int nt = P % NTN, mod = P / NTN;
    int off = mod_off[mod], cnt = mod_off[mod + 1] - off;
    if (mt * 256 >= cnt) return;

    __shared__ __align__(16) f16 As[2][256 * 64];
    __shared__ __align__(16) f16 Bs[2][256 * 64];
    __shared__ int rowtok[256];
    int tid = threadIdx.x, wave = tid >> 6, lane = tid & 63;
    if (tid < 256) {
        int r = mt * 256 + tid;
        rowtok[tid] = (r < cnt) ? sorted_tok[off + r] : -1;
    }
    __syncthreads();
    const f16* Wm = W + (size_t)mod * NW * K;

    // hoisted int32 staging offsets (r11-proven; 8 VGPRs)
    int aoff[2][2], boff[2][2];
#pragma unroll
    for (int h = 0; h < 2; ++h) {
#pragma unroll
        for (int l = 0; l < 2; ++l) {
            int c = l * 512 + tid;
            int rl = c >> 3, kc = c & 7, skc = kc ^ (rl & 7);
            int row = h * 128 + rl;
            int tk = rowtok[row];
            if (tk < 0) tk = 0;
            aoff[h][l] = tk * K + skc * 8;
            int o = nt * 256 + row;
            if (o >= NW) o = NW - 1;
            boff[h][l] = o * K + skc * 8;
        }
    }
    int dsto = tid * 8; // f16 units

    int wr = wave >> 2, wc = wave & 3; // 2 x 4 wave grid
    f32x4 acc[8][4] = {};

    auto STAGE_A = [&](int b, int h, int kt) {
#pragma unroll
        for (int l = 0; l < 2; ++l)
            gload16(A + aoff[h][l] + kt * 64, &As[b][h * 8192 + l * 4096 + dsto]);
    };
    auto STAGE_B = [&](int b, int h, int kt) {
#pragma unroll
        for (int l = 0; l < 2; ++l)
            gload16(Wm + boff[h][l] + kt * 64, &Bs[b][h * 8192 + l * 4096 + dsto]);
    };

    f16x8 bf[2][4]; // [ks][j], held across 4 phases of a K-tile
    auto LOAD_B = [&](int b) {
#pragma unroll
        for (int ks = 0; ks < 2; ++ks)
#pragma unroll
            for (int j = 0; j < 4; ++j) {
                int br = wc * 64 + j * 16 + (lane & 15);
                int bc = (ks * 4 + (lane >> 4)) ^ (br & 7);
                bf[ks][j] = *(const f16x8*)&Bs[b][br * 64 + bc * 8];
            }
    };
    f16x8 af[2][2]; // [ks][i] quadrant fragments
    auto LOAD_A = [&](int b, int q) {
#pragma unroll
        for (int ks = 0; ks < 2; ++ks)
#pragma unroll
            for (int i = 0; i < 2; ++i) {
                int ar = wr * 128 + (q * 2 + i) * 16 + (lane & 15);
                int ac = (ks * 4 + (lane >> 4)) ^ (ar & 7);
                af[ks][i] = *(const f16x8*)&As[b][ar * 64 + ac * 8];
            }
    };
    auto MFMA_Q = [&](int q) {
        __builtin_amdgcn_s_setprio(1);
#pragma unroll
        for (int ks = 0; ks < 2; ++ks)
#pragma unroll
            for (int i = 0; i < 2; ++i)
#pragma unroll
                for (int j = 0; j < 4; ++j)
                    acc[q * 2 + i][j] = __builtin_amdgcn_mfma_f32_16x16x32_f16(
                        af[ks][i], bf[ks][j], acc[q * 2 + i][j], 0, 0, 0);
        __builtin_amdgcn_s_setprio(0);
    };

    // prologue: stage K-tile 0 into buf0 (4 half-tiles, 8 loads outstanding)
    STAGE_A(0, 0, 0); STAGE_A(0, 1, 0); STAGE_B(0, 0, 0); STAGE_B(0, 1, 0);

    for (int it = 0; it < NIT; ++it) {
        int kt0 = 2 * it, kt1 = kt0 + 1;
        // ---- phase 0: gate even tile; stage A.h0(kt1)->buf1; quadrant 0
        STAGE_A(1, 0, kt1);
        asm volatile("s_waitcnt vmcnt(2)" ::: "memory");
        __builtin_amdgcn_s_barrier();
        LOAD_B(0);
        LOAD_A(0, 0);
        MFMA_Q(0);
        asm volatile("" ::: "memory");
        __builtin_amdgcn_s_barrier();
        // ---- phase 1
        LOAD_A(0, 1);
        STAGE_A(1, 1, kt1);
        asm volatile("" ::: "memory");
        __builtin_amdgcn_s_barrier();
        MFMA_Q(1);
        asm volatile("" ::: "memory");
        __builtin_amdgcn_s_barrier();
        // ---- phase 2
        LOAD_A(0, 2);
        STAGE_B(1, 0, kt1);
        asm volatile("" ::: "memory");
        __builtin_amdgcn_s_barrier();
        MFMA_Q(2);
        asm volatile("" ::: "memory");
        __builtin_amdgcn_s_barrier();
        // ---- phase 3
        LOAD_A(0, 3);
        STAGE_B(1, 1, kt1);
        asm volatile("" ::: "memory");
        __builtin_amdgcn_s_barrier();
        MFMA_Q(3);
        asm volatile("" ::: "memory");
        __builtin_amdgcn_s_barrier();
        // ---- phase 4: gate odd tile; stage A.h0(kt0+2)->buf0; quadrant 0
        if (it < NIT - 1) {
            STAGE_A(0, 0, kt0 + 2);
            asm volatile("s_waitcnt vmcnt(2)" ::: "memory");
        } else {
            asm volatile("s_waitcnt vmcnt(0)" ::: "memory");
        }
        __builtin_amdgcn_s_barrier();
        LOAD_B(1);
        LOAD_A(1, 0);
        MFMA_Q(0);
        asm volatile("" ::: "memory");
        __builtin_amdgcn_s_barrier();
        // ---- phase 5
        LOAD_A(1, 1);
        if (it < NIT - 1) STAGE_A(0, 1, kt0 + 2);
        asm volatile("" ::: "memory");
        __builtin_amdgcn_s_barrier();
        MFMA_Q(1);
        asm volatile("" ::: "memory");
        __builtin_amdgcn_s_barrier();
        // ---- phase 6
        LOAD_A(1, 2);
        if (it < NIT - 1) STAGE_B(0, 0, kt0 + 2);
        asm volatile("" ::: "memory");
        __builtin_amdgcn_s_barrier();
        MFMA_Q(2);
        asm volatile("" ::: "memory");
        __builtin_amdgcn_s_barrier();
        // ---- phase 7
        LOAD_A(1, 3);
        if (it < NIT - 1) STAGE_B(0, 1, kt0 + 2);
        asm volatile("" ::: "memory");
        __builtin_amdgcn_s_barrier();
        MFMA_Q(3);
        asm volatile("" ::: "memory");
        __builtin_amdgcn_s_barrier();
    }

    int cl = lane & 15, rg = lane >> 4;
#pragma unroll
    for (int fi = 0; fi < 8; ++fi) {
#pragma unroll
        for (int rr = 0; rr < 4; ++rr) {
            int row = wr * 128 + fi * 16 + rg * 4 + rr;
            int tk = rowtok[row];
            if (tk < 0) continue;
            float* crow = C + (size_t)tk * NW;
#pragma unroll
            for (int j = 0; j < 4; ++j) {
                int o = nt * 256 + wc * 64 + j * 16 + cl;
                if (o < NW) crow[o] = acc[fi][j][rr];
            }
        }
    }
}

// ---------------- stage 5: q/k RMS norm + RoPE + gate ----------------
__global__ void qkv_post(const float* __restrict__ qkv, const int* __restrict__ mod,
                         const float* __restrict__ cosb, const float* __restrict__ sinb,
                         const float* __restrict__ qnorm, const float* __restrict__ knorm,
                         f16* __restrict__ Qb, f16* __restrict__ Kb, float* __restrict__ gateb)
{
    int tok = blockIdx.x, tid = threadIdx.x;
    int wave = tid >> 6, lane = tid & 63;
    int m = mod[tok];
    float c0 = cosb[tok * HD + lane], c1 = cosb[tok * HD + 64 + lane];
    float s0 = sinb[tok * HD + lane], s1 = sinb[tok * HD + 64 + lane];
    const float* row = qkv + (size_t)tok * QKVO;
    for (int u = wave; u < 48; u += 4) {
        int base = (u < 40) ? u * HD : NQH * HD + (u - 40) * HD;
        float x0 = row[base + lane];
        float x1 = row[base + 64 + lane];
        float ss = x0 * x0 + x1 * x1;
        for (int d = 1; d < 64; d <<= 1) ss += __shfl_xor(ss, d, 64);
        float inv = rsqrtf(ss * (1.f / HD) + 1e-6f);
        const float* nw = (u < 40 ? qnorm : knorm) + m * HD;
        float n0 = x0 * inv * nw[lane];
        float n1 = x1 * inv * nw[64 + lane];
        float r0 = n0 * c0 - n1 * s0;
        float r1 = n1 * c1 + n0 * s1;
        if (u < 40) {
            const float sc = 0.08838834764831845f; // 1/sqrt(128)
            r0 *= sc; r1 *= sc;
            Qb[((size_t)u * S_TOK + tok) * HD + lane] = (f16)r0;
            Qb[((size_t)u * S_TOK + tok) * HD + 64 + lane] = (f16)r1;
        } else {
            Kb[((size_t)(u - 40) * S_TOK + tok) * HD + lane] = (f16)r0;
            Kb[((size_t)(u - 40) * S_TOK + tok) * HD + 64 + lane] = (f16)r1;
        }
    }
    if (tid < 40) {
        float g = row[NQH * HD + 2 * NKV * HD + tid];
        gateb[tok * 40 + tid] = 1.f / (1.f + __expf(-g));
    }
}

// ---------------- stage 5b: V transpose -> Vt[g][d][s'] fp16, pi-permuted ----------------
// Within each 64-token block, column c holds V[s = 64*blk + pi(c)][d], pi(c)=16*(c&3)+(c>>2).
__global__ void vtrans(const float* __restrict__ qkv, f16* __restrict__ Vt)
{
    int tc = blockIdx.x; // 0..31 token chunks of 64
    int g = blockIdx.y;  // 0..7
    int tid = threadIdx.x;
    __shared__ float tile[64][129];
#pragma unroll
    for (int it = 0; it < 8; ++it) {
        int idx = it * 256 + tid;
        int r = idx >> 5, c4 = idx & 31;
        float4 v = *(const float4*)(qkv + (size_t)(tc * 64 + r) * QKVO + NQH * HD + NKV * HD + g * HD + c4 * 4);
        tile[r][c4 * 4 + 0] = v.x;
        tile[r][c4 * 4 + 1] = v.y;
        tile[r][c4 * 4 + 2] = v.z;
        tile[r][c4 * 4 + 3] = v.w;
    }
    __syncthreads();
    int d = tid >> 1, half = tid & 1;
    f16* dst = Vt + ((size_t)g * HD + d) * S_TOK + tc * 64;
#pragma unroll
    for (int j = 0; j < 32; ++j) {
        int c = half * 32 + j;
        dst[c] = (f16)tile[16 * (c & 3) + (c >> 2)][d];
    }
}

// ---------------- stage 6: flash attention, 8 waves / QBLK=128 ----------------
// Qb [40][2048][128] (pre-scaled), Kb [8][2048][128], Vt [8][128][2048] (pi-permuted),
// out -> A2 [2048][5120] fp16.
// LDS 80KB: [0,32K)=Q (after qf: [0,16K)=Kbuf1, [16K,32K)=P 8x2KB);
// [32K,48K)=Kbuf0; [48K,64K)=Vbuf0; [64K,80K)=Vbuf1. 2 blocks/CU -> 16 waves/CU.
__global__ __launch_bounds__(512, 4) void attn(
    const f16* __restrict__ Qb, const f16* __restrict__ Kb,
    const f16* __restrict__ Vtb, const float* __restrict__ gateb,
    f16* __restrict__ A2)
{
    int qt = blockIdx.x, h = blockIdx.y, grp = h / 5;
    int tid = threadIdx.x, wave = tid >> 6, lane = tid & 63;
    __shared__ __align__(16) char smem[81920];
    f16* Qs  = (f16*)smem;
    f16* Kb1 = (f16*)smem;                 // [0,16K) after qf extracted
    char* pbase = smem + 16384 + wave * 2048;
    f16* Kb0 = (f16*)(smem + 32768);
    f16* Vb0 = (f16*)(smem + 49152);
    f16* Vb1 = (f16*)(smem + 65536);

    const f16* Qg = Qb + ((size_t)h * S_TOK + qt * 128) * HD;
    const f16* Kg = Kb + (size_t)grp * S_TOK * HD;
    const f16* Vg = Vtb + (size_t)grp * HD * S_TOK;

    // prologue: Q (4/thread), K0 (2/thread), V0 (2/thread)
#pragma unroll
    for (int it = 0; it < 4; ++it) {
        int c = it * 512 + tid, row = c >> 4, kc = c & 15, skc = kc ^ (row & 15);
        gload16(Qg + row * HD + skc * 8, &Qs[c * 8]);
    }
#pragma unroll
    for (int it = 0; it < 2; ++it) {
        int c = it * 512 + tid, row = c >> 4, kc = c & 15, skc = kc ^ (row & 15);
        gload16(Kg + (size_t)row * HD + skc * 8, &Kb0[c * 8]);
    }
#pragma unroll
    for (int it = 0; it < 2; ++it) {
        int c = it * 512 + tid, row = c >> 3, kc = c & 7, skc = kc ^ (row & 7);
        gload16(Vg + (size_t)row * S_TOK + skc * 8, &Vb0[c * 8]);
    }
    asm volatile("s_waitcnt vmcnt(4)" ::: "memory"); // Q done; K0/V0 in flight
    __builtin_amdgcn_s_barrier();
    f16x8 qf[4];
    {
        int row = wave * 16 + (lane & 15);
#pragma unroll
        for (int ks = 0; ks < 4; ++ks) {
            int sk = (ks * 4 + (lane >> 4)) ^ (row & 15);
            qf[ks] = *(const f16x8*)&Qs[row * 128 + sk * 8];
        }
    }
    asm volatile("s_waitcnt lgkmcnt(0)" ::: "memory"); // qf reads retired before Q reused
    __builtin_amdgcn_s_barrier();

    f32x4 o[8] = {};
    float mrow[4] = {-3.0e38f, -3.0e38f, -3.0e38f, -3.0e38f};
    float lrow[4] = {0.f, 0.f, 0.f, 0.f};

    int cur = 0;
    for (int t = 0; t < 32; ++t) {
        f16* Ks = cur ? Kb1 : Kb0;
        f16* Vs = cur ? Vb1 : Vb0;
        if (t < 31) {
            f16* Kn = cur ? Kb0 : Kb1;
            f16* Vn = cur ? Vb0 : Vb1;
#pragma unroll
            for (int it = 0; it < 2; ++it) {
                int c = it * 512 + tid, row = c >> 4, kc = c & 15, skc = kc ^ (row & 15);
                gload16(Kg + (size_t)((t + 1) * 64 + row) * HD + skc * 8, &Kn[c * 8]);
            }
#pragma unroll
            for (int it = 0; it < 2; ++it) {
                int c = it * 512 + tid, row = c >> 3, kc = c & 7, skc = kc ^ (row & 7);
                gload16(Vg + (size_t)row * S_TOK + (t + 1) * 64 + skc * 8, &Vn[c * 8]);
            }
            asm volatile("s_waitcnt vmcnt(4)" ::: "memory"); // drain tile t; keep t+1 in flight
        } else {
            asm volatile("s_waitcnt vmcnt(0)" ::: "memory");
        }
        __builtin_amdgcn_s_barrier();

        f32x4 s[4] = {};
        __builtin_amdgcn_s_setprio(1);
#pragma unroll
        for (int ks = 0; ks < 4; ++ks) {
#pragma unroll
            for (int nj = 0; nj < 4; ++nj) {
                int kr = nj * 16 + (lane & 15);
                int sk = (ks * 4 + (lane >> 4)) ^ (kr & 15);
                f16x8 kf = *(const f16x8*)&Ks[kr * 128 + sk * 8];
                s[nj] = __builtin_amdgcn_mfma_f32_16x16x32_f16(qf[ks], kf, s[nj], 0, 0, 0);
            }
        }
        __builtin_amdgcn_s_setprio(0);
        float mx[4], psum[4];
#pragma unroll
        for (int r = 0; r < 4; ++r)
            mx[r] = fmaxf(fmaxf(s[0][r], s[1][r]), fmaxf(s[2][r], s[3][r]));
        for (int d = 1; d < 16; d <<= 1) {
#pragma unroll
            for (int r = 0; r < 4; ++r) mx[r] = fmaxf(mx[r], __shfl_xor(mx[r], d, 16));
        }
        // defer-max (T13): rescale only when max grew by > 8
        bool need = false;
#pragma unroll
        for (int r = 0; r < 4; ++r) need = need || (mx[r] > mrow[r] + 8.f);
        if (__any(need)) {
#pragma unroll
            for (int r = 0; r < 4; ++r) {
                float nm = fmaxf(mrow[r], mx[r]);
                float corr = __expf(mrow[r] - nm);
                mrow[r] = nm;
                lrow[r] *= corr;
#pragma unroll
                for (int nj2 = 0; nj2 < 8; ++nj2) o[nj2][r] *= corr;
            }
        }
        // P = exp(S - m), packed pi-layout store
#pragma unroll
        for (int r = 0; r < 4; ++r) psum[r] = 0.f;
#pragma unroll
        for (int r = 0; r < 4; ++r) {
            f16x4 hp;
#pragma unroll
            for (int nj = 0; nj < 4; ++nj) {
                float p = __expf(s[nj][r] - mrow[r]);
                psum[r] += p;
                hp[nj] = (f16)p;
            }
            int q = (lane >> 4) * 4 + r;
            int addr = q * 128 + ((8 * (lane & 15)) ^ ((q & 7) << 4));
            *(f16x4*)(pbase + addr) = hp;
        }
        for (int d = 1; d < 16; d <<= 1) {
#pragma unroll
            for (int r = 0; r < 4; ++r) psum[r] += __shfl_xor(psum[r], d, 16);
        }
#pragma unroll
        for (int r = 0; r < 4; ++r) lrow[r] += psum[r];
        __builtin_amdgcn_s_setprio(1);
#pragma unroll
        for (int ks2 = 0; ks2 < 2; ++ks2) {
            int prow = lane & 15;
            int sk = (ks2 * 4 + (lane >> 4)) ^ (prow & 7);
            f16x8 pa = *(const f16x8*)(pbase + prow * 128 + sk * 16);
#pragma unroll
            for (int nj2 = 0; nj2 < 8; ++nj2) {
                int vr = nj2 * 16 + (lane & 15);
                int skv = (ks2 * 4 + (lane >> 4)) ^ (vr & 7);
                f16x8 vf = *(const f16x8*)&Vs[vr * 64 + skv * 8];
                o[nj2] = __builtin_amdgcn_mfma_f32_16x16x32_f16(pa, vf, o[nj2], 0, 0, 0);
            }
        }
        __builtin_amdgcn_s_setprio(0);
        asm volatile("s_waitcnt lgkmcnt(0)" ::: "memory"); // buf[cur] reads retired
        __builtin_amdgcn_s_barrier();
        cur ^= 1;
    }
    int rbase = qt * 128 + wave * 16 + (lane >> 4) * 4;
#pragma unroll
    for (int r = 0; r < 4; ++r) {
        int tok = rbase + r;
        float sc = gateb[tok * 40 + h] / lrow[r];
#pragma unroll
        for (int nj2 = 0; nj2 < 8; ++nj2) {
            int d = nj2 * 16 + (lane & 15);
            A2[(size_t)tok * HID + h * HD + d] = (f16)(o[nj2][r] * sc);
        }
    }
}

extern "C" void kernel_launch(void* const* d_in, const int* in_sizes, int n_in,
                              void* d_out, int out_size, void* d_ws, size_t ws_size,
                              hipStream_t stream)
{
    const float* x = (const float*)d_in[0];
    const float* rc = (const float*)d_in[1];
    const float* rs = (const float*)d_in[2];
    const int* mod = (const int*)d_in[3];
    const float* prenorm = (const float*)d_in[4];
    const float* qkvw = (const float*)d_in[5];
    const float* qn = (const float*)d_in[6];
    const float* kn = (const float*)d_in[7];
    const float* projw = (const float*)d_in[8];
    float* out = (float*)d_out;

    char* p = (char*)d_ws;
    auto alloc = [&](size_t bytes) {
        char* r = p;
        p += (bytes + 255) & ~(size_t)255;
        return r;
    };
    int* sorted = (int*)alloc(S_TOK * 4);
    int* offs = (int*)alloc(16);
    f16* A1 = (f16*)alloc((size_t)S_TOK * HID * 2);
    f16* Wq = (f16*)alloc((size_t)3 * QKVO * HID * 2);
    f16* Wp = (f16*)alloc((size_t)3 * HID * HID * 2);
    float* qkv = (float*)alloc((size_t)S_TOK * QKVO * 4);
    f16* Qb = (f16*)alloc((size_t)NQH * S_TOK * HD * 2);
    f16* Kb = (f16*)alloc((size_t)NKV * S_TOK * HD * 2);
    f16* Vt = (f16*)alloc((size_t)NKV * HD * S_TOK * 2);
    float* gate = (float*)alloc((size_t)S_TOK * 40 * 4);
    f16* A2 = (f16*)alloc((size_t)S_TOK * HID * 2);
    if ((size_t)(p - (char*)d_ws) > ws_size) return; // insufficient workspace

    sort_tokens<<<1, 256, 0, stream>>>(mod, sorted, offs);
    cvt_f32_f16<<<2048, 256, 0, stream>>>(qkvw, Wq, 3 * QKVO * HID / 4);
    cvt_f32_f16<<<2048, 256, 0, stream>>>(projw, Wp, 3 * HID * HID / 4);
    rms_pre<<<2048, 256, 0, stream>>>(x, mod, prenorm, A1);
    {
        int NTN = (QKVO + 255) / 256, NPAN = NTN * 3;   // 29, 87
        int grid = ((NPAN + 7) / 8) * 8 * 8;            // 704
        gemm_grouped8<<<grid, 512, 0, stream>>>(A1, Wq, qkv, sorted, offs, QKVO, NTN, NPAN);
    }
    qkv_post<<<2048, 256, 0, stream>>>(qkv, mod, rc, rs, qn, kn, Qb, Kb, gate);
    vtrans<<<dim3(32, 8), 256, 0, stream>>>(qkv, Vt);
    attn<<<dim3(16, 40), 512, 0, stream>>>(Qb, Kb, Vt, gate, A2);
    {
        int NTN = HID / 256, NPAN = NTN * 3;            // 20, 60
        int grid = ((NPAN + 7) / 8) * 8 * 8;            // 512
        gemm_grouped8<<<grid, 512, 0, stream>>>(A2, Wp, out, sorted, offs, HID, NTN, NPAN);
    }
}

// Round 13
// 829.446 us; speedup vs baseline: 1.1367x; 1.1367x over previous
//
#include <hip/hip_runtime.h>

typedef _Float16 f16;
typedef f16 f16x8 __attribute__((ext_vector_type(8)));
typedef f16 f16x4 __attribute__((ext_vector_type(4)));
typedef float f32x4 __attribute__((ext_vector_type(4)));

#define HID 5120
#define QKVO 7208
#define S_TOK 2048
#define NQH 40
#define NKV 8
#define HD 128

__device__ __forceinline__ void gload16(const void* g, void* l) {
    __builtin_amdgcn_global_load_lds(
        (const __attribute__((address_space(1))) void*)g,
        (__attribute__((address_space(3))) void*)l,
        16, 0, 0);
}

// ---------------- stage 1: stable partition of tokens by modality ----------------
__global__ void sort_tokens(const int* __restrict__ mod, int* __restrict__ sorted,
                            int* __restrict__ offs)
{
    int tid = threadIdx.x, wave = tid >> 6, lane = tid & 63;
    int mloc[8];
    int c[3] = {0, 0, 0};
#pragma unroll
    for (int j = 0; j < 8; ++j) {
        int m = mod[tid * 8 + j];
        mloc[j] = m;
        c[m]++;
    }
    __shared__ int wsum[4][3];
    int excl[3];
#pragma unroll
    for (int m = 0; m < 3; ++m) {
        int v = c[m];
        int incl = v;
        for (int d = 1; d < 64; d <<= 1) {
            int n = __shfl_up(incl, d, 64);
            if (lane >= d) incl += n;
        }
        excl[m] = incl - v;
        if (lane == 63) wsum[wave][m] = incl;
    }
    __syncthreads();
    int wbase[3], tot[3];
#pragma unroll
    for (int m = 0; m < 3; ++m) {
        int b = 0, t = 0;
        for (int w = 0; w < 4; ++w) {
            if (w < wave) b += wsum[w][m];
            t += wsum[w][m];
        }
        wbase[m] = b;
        tot[m] = t;
    }
    int base[3];
    base[0] = 0;
    base[1] = tot[0];
    base[2] = tot[0] + tot[1];
    if (tid == 0) {
        offs[0] = 0;
        offs[1] = tot[0];
        offs[2] = tot[0] + tot[1];
        offs[3] = S_TOK;
    }
    int pos[3];
#pragma unroll
    for (int m = 0; m < 3; ++m) pos[m] = base[m] + wbase[m] + excl[m];
#pragma unroll
    for (int j = 0; j < 8; ++j) {
        int m = mloc[j];
        sorted[pos[m]++] = tid * 8 + j;
    }
}

// ---------------- stage 2: fp32 -> fp16 weight conversion (both weight arrays, one launch) ----------------
__global__ void cvt_weights(const float* __restrict__ s1, f16* __restrict__ d1, int n1,
                            const float* __restrict__ s2, f16* __restrict__ d2, int n2)
{
    int i = blockIdx.x * 256 + threadIdx.x;
    int stride = gridDim.x * 256;
    int ntot = n1 + n2;
    for (; i < ntot; i += stride) {
        const float4* s4;
        f16x4* d4;
        int j;
        if (i < n1) { s4 = (const float4*)s1; d4 = (f16x4*)d1; j = i; }
        else        { s4 = (const float4*)s2; d4 = (f16x4*)d2; j = i - n1; }
        float4 a = s4[j];
        f16x4 h;
        h[0] = (f16)a.x; h[1] = (f16)a.y; h[2] = (f16)a.z; h[3] = (f16)a.w;
        d4[j] = h;
    }
}

// ---------------- stage 3: pre RMS norm -> fp16 activations (token order) ----------------
__global__ void rms_pre(const float* __restrict__ x, const int* __restrict__ mod,
                        const float* __restrict__ prenorm, f16* __restrict__ A1)
{
    int tok = blockIdx.x, tid = threadIdx.x;
    int m = mod[tok];
    const float4* xv = (const float4*)(x + (size_t)tok * HID);
    float4 v[5];
    float ss = 0.f;
#pragma unroll
    for (int j = 0; j < 5; ++j) {
        v[j] = xv[tid + 256 * j];
        ss += v[j].x * v[j].x + v[j].y * v[j].y + v[j].z * v[j].z + v[j].w * v[j].w;
    }
    for (int d = 1; d < 64; d <<= 1) ss += __shfl_xor(ss, d, 64);
    __shared__ float ws[4];
    if ((tid & 63) == 0) ws[tid >> 6] = ss;
    __syncthreads();
    float tot = ws[0] + ws[1] + ws[2] + ws[3];
    float inv = rsqrtf(tot * (1.f / HID) + 1e-6f);
    const float4* wv = (const float4*)(prenorm + (size_t)m * HID);
    f16x4* out4 = (f16x4*)(A1 + (size_t)tok * HID);
#pragma unroll
    for (int j = 0; j < 5; ++j) {
        float4 w = wv[tid + 256 * j];
        f16x4 h;
        h[0] = (f16)(v[j].x * inv * w.x);
        h[1] = (f16)(v[j].y * inv * w.y);
        h[2] = (f16)(v[j].z * inv * w.z);
        h[3] = (f16)(v[j].w * inv * w.w);
        out4[tid + 256 * j] = h;
    }
}

// ---------------- grouped GEMM: C[tok, o] = sum_k A[tok,k] * W[mod][o,k] ----------------
// r11-proven: 128x128/4-wave/2-phase, int32 offset hoist (no spill at VGPR 60),
// XCD-panel-grouped 1-D grid: F = ((P>>3)*16 + mt)*8 + (P&7).
// Templated on output type: f16 for the qkv intermediate, float for final out.
template <typename OT>
__global__ __launch_bounds__(256, 4) void gemm_grouped(
    const f16* __restrict__ A, const f16* __restrict__ W,
    OT* __restrict__ C,
    const int* __restrict__ sorted_tok,
    const int* __restrict__ mod_off, int NW, int NTN, int NPAN)
{
    const int K = HID;
    int F = blockIdx.x;
    int g = F & 7, s = F >> 3;
    int P = (s >> 4) * 8 + g;
    if (P >= NPAN) return;
    int mt = s & 15;
    int nt = P % NTN, mod = P / NTN;
    int off = mod_off[mod], cnt = mod_off[mod + 1] - off;
    if (mt * 128 >= cnt) return;
    __shared__ __align__(16) f16 As[128 * 64];
    __shared__ __align__(16) f16 Bs[128 * 64];
    __shared__ int rowtok[128];
    int tid = threadIdx.x, wave = tid >> 6, lane = tid & 63;
    if (tid < 128) {
        int r = mt * 128 + tid;
        rowtok[tid] = (r < cnt) ? sorted_tok[off + r] : -1;
    }
    __syncthreads();
    const f16* Wm = W + (size_t)mod * NW * K;
    // hoisted int32 staging offsets (loop-invariant; +kt*64 per step)
    int aoff[4], boff[4], dstoff[4];
#pragma unroll
    for (int it = 0; it < 4; ++it) {
        int c = it * 256 + tid;
        int row = c >> 3, kc = c & 7, skc = kc ^ (row & 7);
        dstoff[it] = c * 8;
        int tk = rowtok[row];
        if (tk < 0) tk = 0;
        aoff[it] = tk * K + skc * 8;
        int o = nt * 128 + row;
        if (o >= NW) o = NW - 1;
        boff[it] = o * K + skc * 8;
    }
    int wr = wave >> 1, wc = wave & 1;
    f32x4 acc[4][4] = {};
    for (int kt = 0; kt < K / 64; ++kt) {
        int k0 = kt * 64;
#pragma unroll
        for (int it = 0; it < 4; ++it)
            gload16(A + aoff[it] + k0, &As[dstoff[it]]);
#pragma unroll
        for (int it = 0; it < 4; ++it)
            gload16(Wm + boff[it] + k0, &Bs[dstoff[it]]);
        __syncthreads();
#pragma unroll
        for (int ks = 0; ks < 2; ++ks) {
            f16x8 a[4], b[4];
#pragma unroll
            for (int i = 0; i < 4; ++i) {
                int ar = wr * 64 + i * 16 + (lane & 15);
                int ac = (ks * 4 + (lane >> 4)) ^ (ar & 7);
                a[i] = *(const f16x8*)&As[ar * 64 + ac * 8];
                int br = wc * 64 + i * 16 + (lane & 15);
                int bc = (ks * 4 + (lane >> 4)) ^ (br & 7);
                b[i] = *(const f16x8*)&Bs[br * 64 + bc * 8];
            }
#pragma unroll
            for (int mi = 0; mi < 4; ++mi)
#pragma unroll
                for (int nj = 0; nj < 4; ++nj)
                    acc[mi][nj] = __builtin_amdgcn_mfma_f32_16x16x32_f16(
                        a[mi], b[nj], acc[mi][nj], 0, 0, 0);
        }
        __syncthreads();
    }
    int cl = lane & 15, rg = lane >> 4;
#pragma unroll
    for (int mi = 0; mi < 4; ++mi) {
#pragma unroll
        for (int rr = 0; rr < 4; ++rr) {
            int row = wr * 64 + mi * 16 + rg * 4 + rr;
            int tk = rowtok[row];
            if (tk < 0) continue;
            OT* crow = C + (size_t)tk * NW;
#pragma unroll
            for (int nj = 0; nj < 4; ++nj) {
                int o = nt * 128 + wc * 64 + nj * 16 + cl;
                if (o < NW) crow[o] = (OT)acc[mi][nj][rr];
            }
        }
    }
}

// ---------------- stage 5: q/k RMS norm + RoPE + gate (qkv now f16) ----------------
__global__ void qkv_post(const f16* __restrict__ qkv, const int* __restrict__ mod,
                         const float* __restrict__ cosb, const float* __restrict__ sinb,
                         const float* __restrict__ qnorm, const float* __restrict__ knorm,
                         f16* __restrict__ Qb, f16* __restrict__ Kb, float* __restrict__ gateb)
{
    int tok = blockIdx.x, tid = threadIdx.x;
    int wave = tid >> 6, lane = tid & 63;
    int m = mod[tok];
    float c0 = cosb[tok * HD + lane], c1 = cosb[tok * HD + 64 + lane];
    float s0 = sinb[tok * HD + lane], s1 = sinb[tok * HD + 64 + lane];
    const f16* row = qkv + (size_t)tok * QKVO;
    for (int u = wave; u < 48; u += 4) {
        int base = (u < 40) ? u * HD : NQH * HD + (u - 40) * HD;
        float x0 = (float)row[base + lane];
        float x1 = (float)row[base + 64 + lane];
        float ss = x0 * x0 + x1 * x1;
        for (int d = 1; d < 64; d <<= 1) ss += __shfl_xor(ss, d, 64);
        float inv = rsqrtf(ss * (1.f / HD) + 1e-6f);
        const float* nw = (u < 40 ? qnorm : knorm) + m * HD;
        float n0 = x0 * inv * nw[lane];
        float n1 = x1 * inv * nw[64 + lane];
        float r0 = n0 * c0 - n1 * s0;
        float r1 = n1 * c1 + n0 * s1;
        if (u < 40) {
            const float sc = 0.08838834764831845f; // 1/sqrt(128)
            r0 *= sc; r1 *= sc;
            Qb[((size_t)u * S_TOK + tok) * HD + lane] = (f16)r0;
            Qb[((size_t)u * S_TOK + tok) * HD + 64 + lane] = (f16)r1;
        } else {
            Kb[((size_t)(u - 40) * S_TOK + tok) * HD + lane] = (f16)r0;
            Kb[((size_t)(u - 40) * S_TOK + tok) * HD + 64 + lane] = (f16)r1;
        }
    }
    if (tid < 40) {
        float g = (float)row[NQH * HD + 2 * NKV * HD + tid];
        gateb[tok * 40 + tid] = 1.f / (1.f + __expf(-g));
    }
}

// ---------------- stage 5b: V transpose -> Vt[g][d][s'] f16, pi-permuted ----------------
// Within each 64-token block, column c holds V[s = 64*blk + pi(c)][d], pi(c)=16*(c&3)+(c>>2).
__global__ void vtrans(const f16* __restrict__ qkv, f16* __restrict__ Vt)
{
    int tc = blockIdx.x; // 0..31 token chunks of 64
    int g = blockIdx.y;  // 0..7
    int tid = threadIdx.x;
    __shared__ float tile[64][129];
#pragma unroll
    for (int it = 0; it < 8; ++it) {
        int idx = it * 256 + tid;
        int r = idx >> 5, c4 = idx & 31;
        f16x4 v = *(const f16x4*)(qkv + (size_t)(tc * 64 + r) * QKVO + NQH * HD + NKV * HD + g * HD + c4 * 4);
        tile[r][c4 * 4 + 0] = (float)v[0];
        tile[r][c4 * 4 + 1] = (float)v[1];
        tile[r][c4 * 4 + 2] = (float)v[2];
        tile[r][c4 * 4 + 3] = (float)v[3];
    }
    __syncthreads();
    int d = tid >> 1, half = tid & 1;
    f16* dst = Vt + ((size_t)g * HD + d) * S_TOK + tc * 64;
#pragma unroll
    for (int j = 0; j < 32; ++j) {
        int c = half * 32 + j;
        dst[c] = (f16)tile[16 * (c & 3) + (c >> 2)][d];
    }
}

// ---------------- stage 6: flash attention, 8 waves / QBLK=128 ----------------
// Qb [40][2048][128] (pre-scaled), Kb [8][2048][128], Vt [8][128][2048] (pi-permuted),
// out -> A2 [2048][5120] fp16.
// LDS 80KB: [0,32K)=Q (after qf: [0,16K)=Kbuf1, [16K,32K)=P 8x2KB);
// [32K,48K)=Kbuf0; [48K,64K)=Vbuf0; [64K,80K)=Vbuf1. 2 blocks/CU -> 16 waves/CU.
__global__ __launch_bounds__(512, 4) void attn(
    const f16* __restrict__ Qb, const f16* __restrict__ Kb,
    const f16* __restrict__ Vtb, const float* __restrict__ gateb,
    f16* __restrict__ A2)
{
    int qt = blockIdx.x, h = blockIdx.y, grp = h / 5;
    int tid = threadIdx.x, wave = tid >> 6, lane = tid & 63;
    __shared__ __align__(16) char smem[81920];
    f16* Qs  = (f16*)smem;
    f16* Kb1 = (f16*)smem;                 // [0,16K) after qf extracted
    char* pbase = smem + 16384 + wave * 2048;
    f16* Kb0 = (f16*)(smem + 32768);
    f16* Vb0 = (f16*)(smem + 49152);
    f16* Vb1 = (f16*)(smem + 65536);

    const f16* Qg = Qb + ((size_t)h * S_TOK + qt * 128) * HD;
    const f16* Kg = Kb + (size_t)grp * S_TOK * HD;
    const f16* Vg = Vtb + (size_t)grp * HD * S_TOK;

    // prologue: Q (4/thread), K0 (2/thread), V0 (2/thread)
#pragma unroll
    for (int it = 0; it < 4; ++it) {
        int c = it * 512 + tid, row = c >> 4, kc = c & 15, skc = kc ^ (row & 15);
        gload16(Qg + row * HD + skc * 8, &Qs[c * 8]);
    }
#pragma unroll
    for (int it = 0; it < 2; ++it) {
        int c = it * 512 + tid, row = c >> 4, kc = c & 15, skc = kc ^ (row & 15);
        gload16(Kg + (size_t)row * HD + skc * 8, &Kb0[c * 8]);
    }
#pragma unroll
    for (int it = 0; it < 2; ++it) {
        int c = it * 512 + tid, row = c >> 3, kc = c & 7, skc = kc ^ (row & 7);
        gload16(Vg + (size_t)row * S_TOK + skc * 8, &Vb0[c * 8]);
    }
    asm volatile("s_waitcnt vmcnt(4)" ::: "memory"); // Q done; K0/V0 in flight
    __builtin_amdgcn_s_barrier();
    f16x8 qf[4];
    {
        int row = wave * 16 + (lane & 15);
#pragma unroll
        for (int ks = 0; ks < 4; ++ks) {
            int sk = (ks * 4 + (lane >> 4)) ^ (row & 15);
            qf[ks] = *(const f16x8*)&Qs[row * 128 + sk * 8];
        }
    }
    asm volatile("s_waitcnt lgkmcnt(0)" ::: "memory"); // qf reads retired before Q reused
    __builtin_amdgcn_s_barrier();

    f32x4 o[8] = {};
    float mrow[4] = {-3.0e38f, -3.0e38f, -3.0e38f, -3.0e38f};
    float lrow[4] = {0.f, 0.f, 0.f, 0.f};

    int cur = 0;
    for (int t = 0; t < 32; ++t) {
        f16* Ks = cur ? Kb1 : Kb0;
        f16* Vs = cur ? Vb1 : Vb0;
        if (t < 31) {
            f16* Kn = cur ? Kb0 : Kb1;
            f16* Vn = cur ? Vb0 : Vb1;
#pragma unroll
            for (int it = 0; it < 2; ++it) {
                int c = it * 512 + tid, row = c >> 4, kc = c & 15, skc = kc ^ (row & 15);
                gload16(Kg + (size_t)((t + 1) * 64 + row) * HD + skc * 8, &Kn[c * 8]);
            }
#pragma unroll
            for (int it = 0; it < 2; ++it) {
                int c = it * 512 + tid, row = c >> 3, kc = c & 7, skc = kc ^ (row & 7);
                gload16(Vg + (size_t)row * S_TOK + (t + 1) * 64 + skc * 8, &Vn[c * 8]);
            }
            asm volatile("s_waitcnt vmcnt(4)" ::: "memory"); // drain tile t; keep t+1 in flight
        } else {
            asm volatile("s_waitcnt vmcnt(0)" ::: "memory");
        }
        __builtin_amdgcn_s_barrier();

        f32x4 s[4] = {};
        __builtin_amdgcn_s_setprio(1);
#pragma unroll
        for (int ks = 0; ks < 4; ++ks) {
#pragma unroll
            for (int nj = 0; nj < 4; ++nj) {
                int kr = nj * 16 + (lane & 15);
                int sk = (ks * 4 + (lane >> 4)) ^ (kr & 15);
                f16x8 kf = *(const f16x8*)&Ks[kr * 128 + sk * 8];
                s[nj] = __builtin_amdgcn_mfma_f32_16x16x32_f16(qf[ks], kf, s[nj], 0, 0, 0);
            }
        }
        __builtin_amdgcn_s_setprio(0);
        float mx[4], psum[4];
#pragma unroll
        for (int r = 0; r < 4; ++r)
            mx[r] = fmaxf(fmaxf(s[0][r], s[1][r]), fmaxf(s[2][r], s[3][r]));
        for (int d = 1; d < 16; d <<= 1) {
#pragma unroll
            for (int r = 0; r < 4; ++r) mx[r] = fmaxf(mx[r], __shfl_xor(mx[r], d, 16));
        }
        // defer-max (T13): rescale only when max grew by > 8
        bool need = false;
#pragma unroll
        for (int r = 0; r < 4; ++r) need = need || (mx[r] > mrow[r] + 8.f);
        if (__any(need)) {
#pragma unroll
            for (int r = 0; r < 4; ++r) {
                float nm = fmaxf(mrow[r], mx[r]);
                float corr = __expf(mrow[r] - nm);
                mrow[r] = nm;
                lrow[r] *= corr;
#pragma unroll
                for (int nj2 = 0; nj2 < 8; ++nj2) o[nj2][r] *= corr;
            }
        }
        // P = exp(S - m), packed pi-layout store
#pragma unroll
        for (int r = 0; r < 4; ++r) psum[r] = 0.f;
#pragma unroll
        for (int r = 0; r < 4; ++r) {
            f16x4 hp;
#pragma unroll
            for (int nj = 0; nj < 4; ++nj) {
                float p = __expf(s[nj][r] - mrow[r]);
                psum[r] += p;
                hp[nj] = (f16)p;
            }
            int q = (lane >> 4) * 4 + r;
            int addr = q * 128 + ((8 * (lane & 15)) ^ ((q & 7) << 4));
            *(f16x4*)(pbase + addr) = hp;
        }
        for (int d = 1; d < 16; d <<= 1) {
#pragma unroll
            for (int r = 0; r < 4; ++r) psum[r] += __shfl_xor(psum[r], d, 16);
        }
#pragma unroll
        for (int r = 0; r < 4; ++r) lrow[r] += psum[r];
        __builtin_amdgcn_s_setprio(1);
#pragma unroll
        for (int ks2 = 0; ks2 < 2; ++ks2) {
            int prow = lane & 15;
            int sk = (ks2 * 4 + (lane >> 4)) ^ (prow & 7);
            f16x8 pa = *(const f16x8*)(pbase + prow * 128 + sk * 16);
#pragma unroll
            for (int nj2 = 0; nj2 < 8; ++nj2) {
                int vr = nj2 * 16 + (lane & 15);
                int skv = (ks2 * 4 + (lane >> 4)) ^ (vr & 7);
                f16x8 vf = *(const f16x8*)&Vs[vr * 64 + skv * 8];
                o[nj2] = __builtin_amdgcn_mfma_f32_16x16x32_f16(pa, vf, o[nj2], 0, 0, 0);
            }
        }
        __builtin_amdgcn_s_setprio(0);
        asm volatile("s_waitcnt lgkmcnt(0)" ::: "memory"); // buf[cur] reads retired
        __builtin_amdgcn_s_barrier();
        cur ^= 1;
    }
    int rbase = qt * 128 + wave * 16 + (lane >> 4) * 4;
#pragma unroll
    for (int r = 0; r < 4; ++r) {
        int tok = rbase + r;
        float sc = gateb[tok * 40 + h] / lrow[r];
#pragma unroll
        for (int nj2 = 0; nj2 < 8; ++nj2) {
            int d = nj2 * 16 + (lane & 15);
            A2[(size_t)tok * HID + h * HD + d] = (f16)(o[nj2][r] * sc);
        }
    }
}

extern "C" void kernel_launch(void* const* d_in, const int* in_sizes, int n_in,
                              void* d_out, int out_size, void* d_ws, size_t ws_size,
                              hipStream_t stream)
{
    const float* x = (const float*)d_in[0];
    const float* rc = (const float*)d_in[1];
    const float* rs = (const float*)d_in[2];
    const int* mod = (const int*)d_in[3];
    const float* prenorm = (const float*)d_in[4];
    const float* qkvw = (const float*)d_in[5];
    const float* qn = (const float*)d_in[6];
    const float* kn = (const float*)d_in[7];
    const float* projw = (const float*)d_in[8];
    float* out = (float*)d_out;

    char* p = (char*)d_ws;
    auto alloc = [&](size_t bytes) {
        char* r = p;
        p += (bytes + 255) & ~(size_t)255;
        return r;
    };
    int* sorted = (int*)alloc(S_TOK * 4);
    int* offs = (int*)alloc(16);
    f16* A1 = (f16*)alloc((size_t)S_TOK * HID * 2);
    f16* Wq = (f16*)alloc((size_t)3 * QKVO * HID * 2);
    f16* Wp = (f16*)alloc((size_t)3 * HID * HID * 2);
    f16* qkv = (f16*)alloc((size_t)S_TOK * QKVO * 2);
    f16* Qb = (f16*)alloc((size_t)NQH * S_TOK * HD * 2);
    f16* Kb = (f16*)alloc((size_t)NKV * S_TOK * HD * 2);
    f16* Vt = (f16*)alloc((size_t)NKV * HD * S_TOK * 2);
    float* gate = (float*)alloc((size_t)S_TOK * 40 * 4);
    f16* A2 = (f16*)alloc((size_t)S_TOK * HID * 2);
    if ((size_t)(p - (char*)d_ws) > ws_size) return; // insufficient workspace

    sort_tokens<<<1, 256, 0, stream>>>(mod, sorted, offs);
    cvt_weights<<<3072, 256, 0, stream>>>(qkvw, Wq, 3 * QKVO * HID / 4,
                                          projw, Wp, 3 * HID * HID / 4);
    rms_pre<<<2048, 256, 0, stream>>>(x, mod, prenorm, A1);
    {
        int NTN = 57, NPAN = NTN * 3;                 // qkv panels
        int grid = 8 * ((NPAN + 7) / 8) * 16;         // 2816
        gemm_grouped<f16><<<grid, 256, 0, stream>>>(A1, Wq, qkv, sorted, offs, QKVO, NTN, NPAN);
    }
    qkv_post<<<2048, 256, 0, stream>>>(qkv, mod, rc, rs, qn, kn, Qb, Kb, gate);
    vtrans<<<dim3(32, 8), 256, 0, stream>>>(qkv, Vt);
    attn<<<dim3(16, 40), 512, 0, stream>>>(Qb, Kb, Vt, gate, A2);
    {
        int NTN = 40, NPAN = NTN * 3;                 // proj panels
        int grid = 8 * ((NPAN + 7) / 8) * 16;         // 1920
        gemm_grouped<float><<<grid, 256, 0, stream>>>(A2, Wp, out, sorted, offs, HID, NTN, NPAN);
    }
}

// Round 15
// 821.979 us; speedup vs baseline: 1.1470x; 1.0091x over previous
//
#include <hip/hip_runtime.h>

typedef _Float16 f16;
typedef f16 f16x8 __attribute__((ext_vector_type(8)));
typedef f16 f16x4 __attribute__((ext_vector_type(4)));
typedef float f32x4 __attribute__((ext_vector_type(4)));

#define HID 5120
#define QKVO 7208
#define S_TOK 2048
#define NQH 40
#define NKV 8
#define HD 128

__device__ __forceinline__ void gload16(const void* g, void* l) {
    __builtin_amdgcn_global_load_lds(
        (const __attribute__((address_space(1))) void*)g,
        (__attribute__((address_space(3))) void*)l,
        16, 0, 0);
}

// ---------------- stage 1: stable partition of tokens by modality ----------------
__global__ void sort_tokens(const int* __restrict__ mod, int* __restrict__ sorted,
                            int* __restrict__ offs)
{
    int tid = threadIdx.x, wave = tid >> 6, lane = tid & 63;
    int mloc[8];
    int c[3] = {0, 0, 0};
#pragma unroll
    for (int j = 0; j < 8; ++j) {
        int m = mod[tid * 8 + j];
        mloc[j] = m;
        c[m]++;
    }
    __shared__ int wsum[4][3];
    int excl[3];
#pragma unroll
    for (int m = 0; m < 3; ++m) {
        int v = c[m];
        int incl = v;
        for (int d = 1; d < 64; d <<= 1) {
            int n = __shfl_up(incl, d, 64);
            if (lane >= d) incl += n;
        }
        excl[m] = incl - v;
        if (lane == 63) wsum[wave][m] = incl;
    }
    __syncthreads();
    int wbase[3], tot[3];
#pragma unroll
    for (int m = 0; m < 3; ++m) {
        int b = 0, t = 0;
        for (int w = 0; w < 4; ++w) {
            if (w < wave) b += wsum[w][m];
            t += wsum[w][m];
        }
        wbase[m] = b;
        tot[m] = t;
    }
    int base[3];
    base[0] = 0;
    base[1] = tot[0];
    base[2] = tot[0] + tot[1];
    if (tid == 0) {
        offs[0] = 0;
        offs[1] = tot[0];
        offs[2] = tot[0] + tot[1];
        offs[3] = S_TOK;
    }
    int pos[3];
#pragma unroll
    for (int m = 0; m < 3; ++m) pos[m] = base[m] + wbase[m] + excl[m];
#pragma unroll
    for (int j = 0; j < 8; ++j) {
        int m = mloc[j];
        sorted[pos[m]++] = tid * 8 + j;
    }
}

// ---------------- stage 2: fp32 -> fp16 weight conversion, copy-BW shape ----------------
// 32B read (2x f32x4, nontemporal) -> 16B nontemporal write per thread per iter.
// blockIdx.y selects array (no per-iteration branch).
__global__ void cvt_weights(const float* __restrict__ s1, f16* __restrict__ d1, int n8_1,
                            const float* __restrict__ s2, f16* __restrict__ d2, int n8_2)
{
    const f32x4* s4 = (const f32x4*)(blockIdx.y ? s2 : s1);
    f16x8* d8 = (f16x8*)(blockIdx.y ? d2 : d1);
    int n8 = blockIdx.y ? n8_2 : n8_1;
    int i = blockIdx.x * 256 + threadIdx.x;
    int stride = gridDim.x * 256;
    for (; i < n8; i += stride) {
        f32x4 a = __builtin_nontemporal_load(&s4[2 * i]);
        f32x4 b = __builtin_nontemporal_load(&s4[2 * i + 1]);
        f16x8 h;
        h[0] = (f16)a[0]; h[1] = (f16)a[1]; h[2] = (f16)a[2]; h[3] = (f16)a[3];
        h[4] = (f16)b[0]; h[5] = (f16)b[1]; h[6] = (f16)b[2]; h[7] = (f16)b[3];
        __builtin_nontemporal_store(h, &d8[i]);
    }
}

// ---------------- stage 3: pre RMS norm -> fp16 activations (token order) ----------------
__global__ void rms_pre(const float* __restrict__ x, const int* __restrict__ mod,
                        const float* __restrict__ prenorm, f16* __restrict__ A1)
{
    int tok = blockIdx.x, tid = threadIdx.x;
    int m = mod[tok];
    const float4* xv = (const float4*)(x + (size_t)tok * HID);
    float4 v[5];
    float ss = 0.f;
#pragma unroll
    for (int j = 0; j < 5; ++j) {
        v[j] = xv[tid + 256 * j];
        ss += v[j].x * v[j].x + v[j].y * v[j].y + v[j].z * v[j].z + v[j].w * v[j].w;
    }
    for (int d = 1; d < 64; d <<= 1) ss += __shfl_xor(ss, d, 64);
    __shared__ float ws[4];
    if ((tid & 63) == 0) ws[tid >> 6] = ss;
    __syncthreads();
    float tot = ws[0] + ws[1] + ws[2] + ws[3];
    float inv = rsqrtf(tot * (1.f / HID) + 1e-6f);
    const float4* wv = (const float4*)(prenorm + (size_t)m * HID);
    f16x4* out4 = (f16x4*)(A1 + (size_t)tok * HID);
#pragma unroll
    for (int j = 0; j < 5; ++j) {
        float4 w = wv[tid + 256 * j];
        f16x4 h;
        h[0] = (f16)(v[j].x * inv * w.x);
        h[1] = (f16)(v[j].y * inv * w.y);
        h[2] = (f16)(v[j].z * inv * w.z);
        h[3] = (f16)(v[j].w * inv * w.w);
        out4[tid + 256 * j] = h;
    }
}

// ---------------- grouped GEMM: C[tok, o] = sum_k A[tok,k] * W[mod][o,k] ----------------
// r11-proven: 128x128/4-wave/2-phase, int32 offset hoist (no spill at VGPR 60),
// XCD-panel-grouped 1-D grid: F = ((P>>3)*16 + mt)*8 + (P&7).
// Templated on output type: f16 for the qkv intermediate, float for final out.
template <typename OT>
__global__ __launch_bounds__(256, 4) void gemm_grouped(
    const f16* __restrict__ A, const f16* __restrict__ W,
    OT* __restrict__ C,
    const int* __restrict__ sorted_tok,
    const int* __restrict__ mod_off, int NW, int NTN, int NPAN)
{
    const int K = HID;
    int F = blockIdx.x;
    int g = F & 7, s = F >> 3;
    int P = (s >> 4) * 8 + g;
    if (P >= NPAN) return;
    int mt = s & 15;
    int nt = P % NTN, mod = P / NTN;
    int off = mod_off[mod], cnt = mod_off[mod + 1] - off;
    if (mt * 128 >= cnt) return;
    __shared__ __align__(16) f16 As[128 * 64];
    __shared__ __align__(16) f16 Bs[128 * 64];
    __shared__ int rowtok[128];
    int tid = threadIdx.x, wave = tid >> 6, lane = tid & 63;
    if (tid < 128) {
        int r = mt * 128 + tid;
        rowtok[tid] = (r < cnt) ? sorted_tok[off + r] : -1;
    }
    __syncthreads();
    const f16* Wm = W + (size_t)mod * NW * K;
    // hoisted int32 staging offsets (loop-invariant; +kt*64 per step)
    int aoff[4], boff[4], dstoff[4];
#pragma unroll
    for (int it = 0; it < 4; ++it) {
        int c = it * 256 + tid;
        int row = c >> 3, kc = c & 7, skc = kc ^ (row & 7);
        dstoff[it] = c * 8;
        int tk = rowtok[row];
        if (tk < 0) tk = 0;
        aoff[it] = tk * K + skc * 8;
        int o = nt * 128 + row;
        if (o >= NW) o = NW - 1;
        boff[it] = o * K + skc * 8;
    }
    int wr = wave >> 1, wc = wave & 1;
    f32x4 acc[4][4] = {};
    for (int kt = 0; kt < K / 64; ++kt) {
        int k0 = kt * 64;
#pragma unroll
        for (int it = 0; it < 4; ++it)
            gload16(A + aoff[it] + k0, &As[dstoff[it]]);
#pragma unroll
        for (int it = 0; it < 4; ++it)
            gload16(Wm + boff[it] + k0, &Bs[dstoff[it]]);
        __syncthreads();
#pragma unroll
        for (int ks = 0; ks < 2; ++ks) {
            f16x8 a[4], b[4];
#pragma unroll
            for (int i = 0; i < 4; ++i) {
                int ar = wr * 64 + i * 16 + (lane & 15);
                int ac = (ks * 4 + (lane >> 4)) ^ (ar & 7);
                a[i] = *(const f16x8*)&As[ar * 64 + ac * 8];
                int br = wc * 64 + i * 16 + (lane & 15);
                int bc = (ks * 4 + (lane >> 4)) ^ (br & 7);
                b[i] = *(const f16x8*)&Bs[br * 64 + bc * 8];
            }
#pragma unroll
            for (int mi = 0; mi < 4; ++mi)
#pragma unroll
                for (int nj = 0; nj < 4; ++nj)
                    acc[mi][nj] = __builtin_amdgcn_mfma_f32_16x16x32_f16(
                        a[mi], b[nj], acc[mi][nj], 0, 0, 0);
        }
        __syncthreads();
    }
    int cl = lane & 15, rg = lane >> 4;
#pragma unroll
    for (int mi = 0; mi < 4; ++mi) {
#pragma unroll
        for (int rr = 0; rr < 4; ++rr) {
            int row = wr * 64 + mi * 16 + rg * 4 + rr;
            int tk = rowtok[row];
            if (tk < 0) continue;
            OT* crow = C + (size_t)tk * NW;
#pragma unroll
            for (int nj = 0; nj < 4; ++nj) {
                int o = nt * 128 + wc * 64 + nj * 16 + cl;
                if (o < NW) crow[o] = (OT)acc[mi][nj][rr];
            }
        }
    }
}

// ---------------- stage 5: q/k RMS norm + RoPE + gate (qkv f16) ----------------
__global__ void qkv_post(const f16* __restrict__ qkv, const int* __restrict__ mod,
                         const float* __restrict__ cosb, const float* __restrict__ sinb,
                         const float* __restrict__ qnorm, const float* __restrict__ knorm,
                         f16* __restrict__ Qb, f16* __restrict__ Kb, float* __restrict__ gateb)
{
    int tok = blockIdx.x, tid = threadIdx.x;
    int wave = tid >> 6, lane = tid & 63;
    int m = mod[tok];
    float c0 = cosb[tok * HD + lane], c1 = cosb[tok * HD + 64 + lane];
    float s0 = sinb[tok * HD + lane], s1 = sinb[tok * HD + 64 + lane];
    const f16* row = qkv + (size_t)tok * QKVO;
    for (int u = wave; u < 48; u += 4) {
        int base = (u < 40) ? u * HD : NQH * HD + (u - 40) * HD;
        float x0 = (float)row[base + lane];
        float x1 = (float)row[base + 64 + lane];
        float ss = x0 * x0 + x1 * x1;
        for (int d = 1; d < 64; d <<= 1) ss += __shfl_xor(ss, d, 64);
        float inv = rsqrtf(ss * (1.f / HD) + 1e-6f);
        const float* nw = (u < 40 ? qnorm : knorm) + m * HD;
        float n0 = x0 * inv * nw[lane];
        float n1 = x1 * inv * nw[64 + lane];
        float r0 = n0 * c0 - n1 * s0;
        float r1 = n1 * c1 + n0 * s1;
        if (u < 40) {
            const float sc = 0.08838834764831845f; // 1/sqrt(128)
            r0 *= sc; r1 *= sc;
            Qb[((size_t)u * S_TOK + tok) * HD + lane] = (f16)r0;
            Qb[((size_t)u * S_TOK + tok) * HD + 64 + lane] = (f16)r1;
        } else {
            Kb[((size_t)(u - 40) * S_TOK + tok) * HD + lane] = (f16)r0;
            Kb[((size_t)(u - 40) * S_TOK + tok) * HD + 64 + lane] = (f16)r1;
        }
    }
    if (tid < 40) {
        float g = (float)row[NQH * HD + 2 * NKV * HD + tid];
        gateb[tok * 40 + tid] = 1.f / (1.f + __expf(-g));
    }
}

// ---------------- stage 5b: V transpose -> Vt[g][d][s'] f16, pi-permuted ----------------
// Within each 64-token block, column c holds V[s = 64*blk + pi(c)][d], pi(c)=16*(c&3)+(c>>2).
__global__ void vtrans(const f16* __restrict__ qkv, f16* __restrict__ Vt)
{
    int tc = blockIdx.x; // 0..31 token chunks of 64
    int g = blockIdx.y;  // 0..7
    int tid = threadIdx.x;
    __shared__ float tile[64][129];
#pragma unroll
    for (int it = 0; it < 8; ++it) {
        int idx = it * 256 + tid;
        int r = idx >> 5, c4 = idx & 31;
        f16x4 v = *(const f16x4*)(qkv + (size_t)(tc * 64 + r) * QKVO + NQH * HD + NKV * HD + g * HD + c4 * 4);
        tile[r][c4 * 4 + 0] = (float)v[0];
        tile[r][c4 * 4 + 1] = (float)v[1];
        tile[r][c4 * 4 + 2] = (float)v[2];
        tile[r][c4 * 4 + 3] = (float)v[3];
    }
    __syncthreads();
    int d = tid >> 1, half = tid & 1;
    f16* dst = Vt + ((size_t)g * HD + d) * S_TOK + tc * 64;
#pragma unroll
    for (int j = 0; j < 32; ++j) {
        int c = half * 32 + j;
        dst[c] = (f16)tile[16 * (c & 3) + (c >> 2)][d];
    }
}

// ---------------- stage 6: flash attention, 8 waves / QBLK=128 ----------------
// Qb [40][2048][128] (pre-scaled), Kb [8][2048][128], Vt [8][128][2048] (pi-permuted),
// out -> A2 [2048][5120] fp16.
// LDS 80KB: [0,32K)=Q (after qf: [0,16K)=Kbuf1, [16K,32K)=P 8x2KB);
// [32K,48K)=Kbuf0; [48K,64K)=Vbuf0; [64K,80K)=Vbuf1. 2 blocks/CU -> 16 waves/CU.
__global__ __launch_bounds__(512, 4) void attn(
    const f16* __restrict__ Qb, const f16* __restrict__ Kb,
    const f16* __restrict__ Vtb, const float* __restrict__ gateb,
    f16* __restrict__ A2)
{
    int qt = blockIdx.x, h = blockIdx.y, grp = h / 5;
    int tid = threadIdx.x, wave = tid >> 6, lane = tid & 63;
    __shared__ __align__(16) char smem[81920];
    f16* Qs  = (f16*)smem;
    f16* Kb1 = (f16*)smem;                 // [0,16K) after qf extracted
    char* pbase = smem + 16384 + wave * 2048;
    f16* Kb0 = (f16*)(smem + 32768);
    f16* Vb0 = (f16*)(smem + 49152);
    f16* Vb1 = (f16*)(smem + 65536);

    const f16* Qg = Qb + ((size_t)h * S_TOK + qt * 128) * HD;
    const f16* Kg = Kb + (size_t)grp * S_TOK * HD;
    const f16* Vg = Vtb + (size_t)grp * HD * S_TOK;

    // prologue: Q (4/thread), K0 (2/thread), V0 (2/thread)
#pragma unroll
    for (int it = 0; it < 4; ++it) {
        int c = it * 512 + tid, row = c >> 4, kc = c & 15, skc = kc ^ (row & 15);
        gload16(Qg + row * HD + skc * 8, &Qs[c * 8]);
    }
#pragma unroll
    for (int it = 0; it < 2; ++it) {
        int c = it * 512 + tid, row = c >> 4, kc = c & 15, skc = kc ^ (row & 15);
        gload16(Kg + (size_t)row * HD + skc * 8, &Kb0[c * 8]);
    }
#pragma unroll
    for (int it = 0; it < 2; ++it) {
        int c = it * 512 + tid, row = c >> 3, kc = c & 7, skc = kc ^ (row & 7);
        gload16(Vg + (size_t)row * S_TOK + skc * 8, &Vb0[c * 8]);
    }
    asm volatile("s_waitcnt vmcnt(4)" ::: "memory"); // Q done; K0/V0 in flight
    __builtin_amdgcn_s_barrier();
    f16x8 qf[4];
    {
        int row = wave * 16 + (lane & 15);
#pragma unroll
        for (int ks = 0; ks < 4; ++ks) {
            int sk = (ks * 4 + (lane >> 4)) ^ (row & 15);
            qf[ks] = *(const f16x8*)&Qs[row * 128 + sk * 8];
        }
    }
    asm volatile("s_waitcnt lgkmcnt(0)" ::: "memory"); // qf reads retired before Q reused
    __builtin_amdgcn_s_barrier();

    f32x4 o[8] = {};
    float mrow[4] = {-3.0e38f, -3.0e38f, -3.0e38f, -3.0e38f};
    float lrow[4] = {0.f, 0.f, 0.f, 0.f};

    int cur = 0;
    for (int t = 0; t < 32; ++t) {
        f16* Ks = cur ? Kb1 : Kb0;
        f16* Vs = cur ? Vb1 : Vb0;
        if (t < 31) {
            f16* Kn = cur ? Kb0 : Kb1;
            f16* Vn = cur ? Vb0 : Vb1;
#pragma unroll
            for (int it = 0; it < 2; ++it) {
                int c = it * 512 + tid, row = c >> 4, kc = c & 15, skc = kc ^ (row & 15);
                gload16(Kg + (size_t)((t + 1) * 64 + row) * HD + skc * 8, &Kn[c * 8]);
            }
#pragma unroll
            for (int it = 0; it < 2; ++it) {
                int c = it * 512 + tid, row = c >> 3, kc = c & 7, skc = kc ^ (row & 7);
                gload16(Vg + (size_t)row * S_TOK + (t + 1) * 64 + skc * 8, &Vn[c * 8]);
            }
            asm volatile("s_waitcnt vmcnt(4)" ::: "memory"); // drain tile t; keep t+1 in flight
        } else {
            asm volatile("s_waitcnt vmcnt(0)" ::: "memory");
        }
        __builtin_amdgcn_s_barrier();

        f32x4 s[4] = {};
        __builtin_amdgcn_s_setprio(1);
#pragma unroll
        for (int ks = 0; ks < 4; ++ks) {
#pragma unroll
            for (int nj = 0; nj < 4; ++nj) {
                int kr = nj * 16 + (lane & 15);
                int sk = (ks * 4 + (lane >> 4)) ^ (kr & 15);
                f16x8 kf = *(const f16x8*)&Ks[kr * 128 + sk * 8];
                s[nj] = __builtin_amdgcn_mfma_f32_16x16x32_f16(qf[ks], kf, s[nj], 0, 0, 0);
            }
        }
        __builtin_amdgcn_s_setprio(0);
        float mx[4], psum[4];
#pragma unroll
        for (int r = 0; r < 4; ++r)
            mx[r] = fmaxf(fmaxf(s[0][r], s[1][r]), fmaxf(s[2][r], s[3][r]));
        for (int d = 1; d < 16; d <<= 1) {
#pragma unroll
            for (int r = 0; r < 4; ++r) mx[r] = fmaxf(mx[r], __shfl_xor(mx[r], d, 16));
        }
        // defer-max (T13): rescale only when max grew by > 8
        bool need = false;
#pragma unroll
        for (int r = 0; r < 4; ++r) need = need || (mx[r] > mrow[r] + 8.f);
        if (__any(need)) {
#pragma unroll
            for (int r = 0; r < 4; ++r) {
                float nm = fmaxf(mrow[r], mx[r]);
                float corr = __expf(mrow[r] - nm);
                mrow[r] = nm;
                lrow[r] *= corr;
#pragma unroll
                for (int nj2 = 0; nj2 < 8; ++nj2) o[nj2][r] *= corr;
            }
        }
        // P = exp(S - m), packed pi-layout store
#pragma unroll
        for (int r = 0; r < 4; ++r) psum[r] = 0.f;
#pragma unroll
        for (int r = 0; r < 4; ++r) {
            f16x4 hp;
#pragma unroll
            for (int nj = 0; nj < 4; ++nj) {
                float p = __expf(s[nj][r] - mrow[r]);
                psum[r] += p;
                hp[nj] = (f16)p;
            }
            int q = (lane >> 4) * 4 + r;
            int addr = q * 128 + ((8 * (lane & 15)) ^ ((q & 7) << 4));
            *(f16x4*)(pbase + addr) = hp;
        }
        for (int d = 1; d < 16; d <<= 1) {
#pragma unroll
            for (int r = 0; r < 4; ++r) psum[r] += __shfl_xor(psum[r], d, 16);
        }
#pragma unroll
        for (int r = 0; r < 4; ++r) lrow[r] += psum[r];
        __builtin_amdgcn_s_setprio(1);
#pragma unroll
        for (int ks2 = 0; ks2 < 2; ++ks2) {
            int prow = lane & 15;
            int sk = (ks2 * 4 + (lane >> 4)) ^ (prow & 7);
            f16x8 pa = *(const f16x8*)(pbase + prow * 128 + sk * 16);
#pragma unroll
            for (int nj2 = 0; nj2 < 8; ++nj2) {
                int vr = nj2 * 16 + (lane & 15);
                int skv = (ks2 * 4 + (lane >> 4)) ^ (vr & 7);
                f16x8 vf = *(const f16x8*)&Vs[vr * 64 + skv * 8];
                o[nj2] = __builtin_amdgcn_mfma_f32_16x16x32_f16(pa, vf, o[nj2], 0, 0, 0);
            }
        }
        __builtin_amdgcn_s_setprio(0);
        asm volatile("s_waitcnt lgkmcnt(0)" ::: "memory"); // buf[cur] reads retired
        __builtin_amdgcn_s_barrier();
        cur ^= 1;
    }
    int rbase = qt * 128 + wave * 16 + (lane >> 4) * 4;
#pragma unroll
    for (int r = 0; r < 4; ++r) {
        int tok = rbase + r;
        float sc = gateb[tok * 40 + h] / lrow[r];
#pragma unroll
        for (int nj2 = 0; nj2 < 8; ++nj2) {
            int d = nj2 * 16 + (lane & 15);
            A2[(size_t)tok * HID + h * HD + d] = (f16)(o[nj2][r] * sc);
        }
    }
}

extern "C" void kernel_launch(void* const* d_in, const int* in_sizes, int n_in,
                              void* d_out, int out_size, void* d_ws, size_t ws_size,
                              hipStream_t stream)
{
    const float* x = (const float*)d_in[0];
    const float* rc = (const float*)d_in[1];
    const float* rs = (const float*)d_in[2];
    const int* mod = (const int*)d_in[3];
    const float* prenorm = (const float*)d_in[4];
    const float* qkvw = (const float*)d_in[5];
    const float* qn = (const float*)d_in[6];
    const float* kn = (const float*)d_in[7];
    const float* projw = (const float*)d_in[8];
    float* out = (float*)d_out;

    char* p = (char*)d_ws;
    auto alloc = [&](size_t bytes) {
        char* r = p;
        p += (bytes + 255) & ~(size_t)255;
        return r;
    };
    int* sorted = (int*)alloc(S_TOK * 4);
    int* offs = (int*)alloc(16);
    f16* A1 = (f16*)alloc((size_t)S_TOK * HID * 2);
    f16* Wq = (f16*)alloc((size_t)3 * QKVO * HID * 2);
    f16* Wp = (f16*)alloc((size_t)3 * HID * HID * 2);
    f16* qkv = (f16*)alloc((size_t)S_TOK * QKVO * 2);
    f16* Qb = (f16*)alloc((size_t)NQH * S_TOK * HD * 2);
    f16* Kb = (f16*)alloc((size_t)NKV * S_TOK * HD * 2);
    f16* Vt = (f16*)alloc((size_t)NKV * HD * S_TOK * 2);
    float* gate = (float*)alloc((size_t)S_TOK * 40 * 4);
    f16* A2 = (f16*)alloc((size_t)S_TOK * HID * 2);
    if ((size_t)(p - (char*)d_ws) > ws_size) return; // insufficient workspace

    sort_tokens<<<1, 256, 0, stream>>>(mod, sorted, offs);
    cvt_weights<<<dim3(2048, 2), 256, 0, stream>>>(qkvw, Wq, 3 * QKVO * HID / 8,
                                                   projw, Wp, 3 * HID * HID / 8);
    rms_pre<<<2048, 256, 0, stream>>>(x, mod, prenorm, A1);
    {
        int NTN = 57, NPAN = NTN * 3;                 // qkv panels
        int grid = 8 * ((NPAN + 7) / 8) * 16;         // 2816
        gemm_grouped<f16><<<grid, 256, 0, stream>>>(A1, Wq, qkv, sorted, offs, QKVO, NTN, NPAN);
    }
    qkv_post<<<2048, 256, 0, stream>>>(qkv, mod, rc, rs, qn, kn, Qb, Kb, gate);
    vtrans<<<dim3(32, 8), 256, 0, stream>>>(qkv, Vt);
    attn<<<dim3(16, 40), 512, 0, stream>>>(Qb, Kb, Vt, gate, A2);
    {
        int NTN = 40, NPAN = NTN * 3;                 // proj panels
        int grid = 8 * ((NPAN + 7) / 8) * 16;         // 1920
        gemm_grouped<float><<<grid, 256, 0, stream>>>(A2, Wp, out, sorted, offs, HID, NTN, NPAN);
    }
}